// Round 4
// baseline (2082.055 us; speedup 1.0000x reference)
//
#include <hip/hip_runtime.h>
#include <hip/hip_bf16.h>
#include <stdint.h>

typedef __bf16 bf16x8 __attribute__((ext_vector_type(8)));
typedef __bf16 bf16x4 __attribute__((ext_vector_type(4)));
typedef float  f32x4  __attribute__((ext_vector_type(4)));

#define DIN   128
#define KA    384
#define HD    512
#define NB    1152
#define DOUTD 128
#define NOBJ  50000
#define NTRI  200000
#define TM    64

// ---------------- edges normalization (int32/int64 auto-detect, clamp) ----------------
__global__ void detect_i64(const int* __restrict__ e, int* __restrict__ flag) {
    int i = blockIdx.x * 256 + threadIdx.x;
    if (i < NTRI && e[2 * i + 1] != 0) atomicOr(flag, 1);   // odd words nonzero => int32 layout
}
__global__ void normalize_edges(const int* __restrict__ e, const int* __restrict__ flag,
                                int* __restrict__ sidx, int* __restrict__ oidx) {
    int t = blockIdx.x * 256 + threadIdx.x;
    if (t >= NTRI) return;
    bool is64 = (*flag == 0);
    int s = is64 ? e[4 * t]     : e[2 * t];
    int o = is64 ? e[4 * t + 2] : e[2 * t + 1];
    s = s < 0 ? 0 : (s >= NOBJ ? NOBJ - 1 : s);
    o = o < 0 ? 0 : (o >= NOBJ ? NOBJ - 1 : o);
    sidx[t] = s; oidx[t] = o;
}

// ---------------- weight packing: f32 row-major (K,N) -> bf16 MFMA B-fragments ----------------
// frag f = kt*(N/16) + nt ; lane l holds W[kt*32 + (l>>4)*8 + i][nt*16 + (l&15)], i=0..7
__global__ void pack_w(const float* __restrict__ W, __bf16* __restrict__ P, int K, int N) {
    int idx = blockIdx.x * 256 + threadIdx.x;
    int total = (K / 32) * (N / 16) * 64;
    if (idx >= total) return;
    int lane = idx & 63;
    int f    = idx >> 6;
    int NT   = N / 16;
    int kt = f / NT, nt = f - kt * NT;
    int krow = kt * 32 + (lane >> 4) * 8;
    int col  = nt * 16 + (lane & 15);
    __bf16 tmp[8];
#pragma unroll
    for (int i = 0; i < 8; i++) tmp[i] = (__bf16)W[(size_t)(krow + i) * N + col];
    *reinterpret_cast<bf16x8*>(P + (size_t)idx * 8) = *reinterpret_cast<const bf16x8*>(tmp);
}

// ---------------- per-object degree counts ----------------
__global__ void count_k(const int* __restrict__ sidx, const int* __restrict__ oidx,
                        float* __restrict__ counts) {
    int t = blockIdx.x * 256 + threadIdx.x;
    if (t >= NTRI) return;
    atomicAdd(&counts[sidx[t]], 1.0f);
    atomicAdd(&counts[oidx[t]], 1.0f);
}

// ---------------- fused GEMM1 + GEMM2 + scatter ----------------
#define SA_STRIDE 392
#define SH_STRIDE 520
__global__ __launch_bounds__(512) void fused12(
    const float* __restrict__ obj, const float* __restrict__ pred,
    const int* __restrict__ sidx, const int* __restrict__ oidx,
    const __bf16* __restrict__ pW1a, const float* __restrict__ b1a,
    const __bf16* __restrict__ pW1b, const float* __restrict__ b1b,
    float* __restrict__ pooled, float* __restrict__ out_p,
    int obj_lo, int obj_hi, int write_p)
{
    extern __shared__ char smem[];
    __bf16* sA = (__bf16*)smem;                          // 64*392*2 = 50176 B
    __bf16* sH = (__bf16*)(smem + 64 * SA_STRIDE * 2);   // 64*520*2 = 66560 B

    const int tid  = threadIdx.x;
    const int lane = tid & 63;
    const int wid  = tid >> 6;
    const int t0   = blockIdx.x * TM;

    // ---- Phase 1: gather cur_t tile (f32 -> bf16) into LDS ----
    for (int u = tid; u < 64 * 96; u += 512) {
        int part = u & 31;
        int seg  = (u >> 5) % 3;
        int row  = u / 96;
        int t    = t0 + row;
        const float* src;
        if (seg == 0)      src = obj  + (size_t)sidx[t] * DIN;
        else if (seg == 1) src = pred + (size_t)t       * DIN;
        else               src = obj  + (size_t)oidx[t] * DIN;
        float4 v = *reinterpret_cast<const float4*>(src + part * 4);
        bf16x4 w;
        w[0] = (__bf16)v.x; w[1] = (__bf16)v.y; w[2] = (__bf16)v.z; w[3] = (__bf16)v.w;
        *reinterpret_cast<bf16x4*>(sA + row * SA_STRIDE + seg * 128 + part * 4) = w;
    }
    __syncthreads();

    const int wm = wid >> 2;
    const int wn = wid & 3;
    const int lk = (lane >> 4) * 8;
    const int lr = lane & 15;
    const int rbase = (lane >> 4) * 4;

    // ---- Phase 2: h = relu(cur_t @ W1a + b1a), 64x512 ----
    {
        f32x4 acc[2][8];
#pragma unroll
        for (int mi = 0; mi < 2; mi++)
#pragma unroll
            for (int ni = 0; ni < 8; ni++) acc[mi][ni] = (f32x4){0.f, 0.f, 0.f, 0.f};

        for (int kt = 0; kt < KA / 32; ++kt) {
            bf16x8 a0 = *reinterpret_cast<const bf16x8*>(sA + (wm * 32 + lr) * SA_STRIDE + kt * 32 + lk);
            bf16x8 a1 = *reinterpret_cast<const bf16x8*>(sA + (wm * 32 + 16 + lr) * SA_STRIDE + kt * 32 + lk);
#pragma unroll
            for (int ni = 0; ni < 8; ni++) {
                int f = kt * 32 + wn * 8 + ni;
                bf16x8 b = *reinterpret_cast<const bf16x8*>(pW1a + ((size_t)f * 64 + lane) * 8);
                acc[0][ni] = __builtin_amdgcn_mfma_f32_16x16x32_bf16(a0, b, acc[0][ni], 0, 0, 0);
                acc[1][ni] = __builtin_amdgcn_mfma_f32_16x16x32_bf16(a1, b, acc[1][ni], 0, 0, 0);
            }
        }
#pragma unroll
        for (int mi = 0; mi < 2; mi++)
#pragma unroll
            for (int ni = 0; ni < 8; ni++) {
                int col = wn * 128 + ni * 16 + lr;
                float bv = b1a[col];
#pragma unroll
                for (int r = 0; r < 4; r++) {
                    float v = acc[mi][ni][r] + bv;
                    v = v > 0.f ? v : 0.f;
                    sH[(wm * 32 + mi * 16 + rbase + r) * SH_STRIDE + col] = (__bf16)v;
                }
            }
    }
    __syncthreads();

    // ---- Phase 3: new_t = relu(h @ W1b + b1b), 64x1152; route ----
    {
        f32x4 acc2[2][18];
#pragma unroll
        for (int mi = 0; mi < 2; mi++)
#pragma unroll
            for (int ni = 0; ni < 18; ni++) acc2[mi][ni] = (f32x4){0.f, 0.f, 0.f, 0.f};

        for (int kt = 0; kt < HD / 32; ++kt) {
            bf16x8 a0 = *reinterpret_cast<const bf16x8*>(sH + (wm * 32 + lr) * SH_STRIDE + kt * 32 + lk);
            bf16x8 a1 = *reinterpret_cast<const bf16x8*>(sH + (wm * 32 + 16 + lr) * SH_STRIDE + kt * 32 + lk);
#pragma unroll
            for (int ni = 0; ni < 18; ni++) {
                int f = kt * 72 + wn * 18 + ni;
                bf16x8 b = *reinterpret_cast<const bf16x8*>(pW1b + ((size_t)f * 64 + lane) * 8);
                acc2[0][ni] = __builtin_amdgcn_mfma_f32_16x16x32_bf16(a0, b, acc2[0][ni], 0, 0, 0);
                acc2[1][ni] = __builtin_amdgcn_mfma_f32_16x16x32_bf16(a1, b, acc2[1][ni], 0, 0, 0);
            }
        }
#pragma unroll
        for (int mi = 0; mi < 2; mi++) {
#pragma unroll
            for (int r = 0; r < 4; r++) {
                int row = wm * 32 + mi * 16 + rbase + r;
                int t   = t0 + row;
                int si  = sidx[t];
                int oi  = oidx[t];
#pragma unroll
                for (int ni = 0; ni < 18; ni++) {
                    int c = wn * 288 + ni * 16 + lr;
                    float v = acc2[mi][ni][r] + b1b[c];
                    v = v > 0.f ? v : 0.f;
                    if (c < HD) {
                        if (si >= obj_lo && si < obj_hi)
                            atomicAdd(pooled + (size_t)(si - obj_lo) * HD + c, v);
                    } else if (c < HD + DOUTD) {
                        if (write_p)
                            out_p[(size_t)t * DOUTD + (c - HD)] = v;
                    } else {
                        if (oi >= obj_lo && oi < obj_hi)
                            atomicAdd(pooled + (size_t)(oi - obj_lo) * HD + (c - HD - DOUTD), v);
                    }
                }
            }
        }
    }
}

// ---------------- fused GEMM3 + GEMM4 ----------------
__global__ __launch_bounds__(512) void fused34(
    const float* __restrict__ pooled, const float* __restrict__ counts,
    const __bf16* __restrict__ pW2a, const float* __restrict__ b2a,
    const __bf16* __restrict__ pW2b, const float* __restrict__ b2b,
    float* __restrict__ out_obj, int obj_lo, int obj_hi)
{
    extern __shared__ char smem[];
    __bf16* sX  = (__bf16*)smem;
    __bf16* sH2 = (__bf16*)(smem + 64 * SH_STRIDE * 2);

    const int tid  = threadIdx.x;
    const int lane = tid & 63;
    const int wid  = tid >> 6;
    const int o0   = obj_lo + blockIdx.x * TM;

    // ---- Phase 1: x = pooled / max(counts,1) -> bf16 LDS tile ----
    for (int u = tid; u < 64 * 128; u += 512) {
        int part = u & 127;
        int row  = u >> 7;
        int ob   = o0 + row;
        float4 v = {0.f, 0.f, 0.f, 0.f};
        float inv = 1.f;
        if (ob < obj_hi) {
            v = *reinterpret_cast<const float4*>(pooled + (size_t)(ob - obj_lo) * HD + part * 4);
            float c = counts[ob];
            inv = 1.f / (c > 1.f ? c : 1.f);
        }
        bf16x4 w;
        w[0] = (__bf16)(v.x * inv); w[1] = (__bf16)(v.y * inv);
        w[2] = (__bf16)(v.z * inv); w[3] = (__bf16)(v.w * inv);
        *reinterpret_cast<bf16x4*>(sX + row * SH_STRIDE + part * 4) = w;
    }
    __syncthreads();

    const int wm = wid >> 2;
    const int wn = wid & 3;
    const int lk = (lane >> 4) * 8;
    const int lr = lane & 15;
    const int rbase = (lane >> 4) * 4;

    // ---- Phase 2: h2 = relu(x @ W2a + b2a), 64x512 ----
    {
        f32x4 acc[2][8];
#pragma unroll
        for (int mi = 0; mi < 2; mi++)
#pragma unroll
            for (int ni = 0; ni < 8; ni++) acc[mi][ni] = (f32x4){0.f, 0.f, 0.f, 0.f};

        for (int kt = 0; kt < HD / 32; ++kt) {
            bf16x8 a0 = *reinterpret_cast<const bf16x8*>(sX + (wm * 32 + lr) * SH_STRIDE + kt * 32 + lk);
            bf16x8 a1 = *reinterpret_cast<const bf16x8*>(sX + (wm * 32 + 16 + lr) * SH_STRIDE + kt * 32 + lk);
#pragma unroll
            for (int ni = 0; ni < 8; ni++) {
                int f = kt * 32 + wn * 8 + ni;
                bf16x8 b = *reinterpret_cast<const bf16x8*>(pW2a + ((size_t)f * 64 + lane) * 8);
                acc[0][ni] = __builtin_amdgcn_mfma_f32_16x16x32_bf16(a0, b, acc[0][ni], 0, 0, 0);
                acc[1][ni] = __builtin_amdgcn_mfma_f32_16x16x32_bf16(a1, b, acc[1][ni], 0, 0, 0);
            }
        }
#pragma unroll
        for (int mi = 0; mi < 2; mi++)
#pragma unroll
            for (int ni = 0; ni < 8; ni++) {
                int col = wn * 128 + ni * 16 + lr;
                float bv = b2a[col];
#pragma unroll
                for (int r = 0; r < 4; r++) {
                    float v = acc[mi][ni][r] + bv;
                    v = v > 0.f ? v : 0.f;
                    sH2[(wm * 32 + mi * 16 + rbase + r) * SH_STRIDE + col] = (__bf16)v;
                }
            }
    }
    __syncthreads();

    // ---- Phase 3: new_obj = relu(h2 @ W2b + b2b), 64x128 ----
    {
        f32x4 acc[2][2];
#pragma unroll
        for (int mi = 0; mi < 2; mi++)
#pragma unroll
            for (int ni = 0; ni < 2; ni++) acc[mi][ni] = (f32x4){0.f, 0.f, 0.f, 0.f};

        for (int kt = 0; kt < HD / 32; ++kt) {
            bf16x8 a0 = *reinterpret_cast<const bf16x8*>(sH2 + (wm * 32 + lr) * SH_STRIDE + kt * 32 + lk);
            bf16x8 a1 = *reinterpret_cast<const bf16x8*>(sH2 + (wm * 32 + 16 + lr) * SH_STRIDE + kt * 32 + lk);
#pragma unroll
            for (int ni = 0; ni < 2; ni++) {
                int f = kt * 8 + wn * 2 + ni;
                bf16x8 b = *reinterpret_cast<const bf16x8*>(pW2b + ((size_t)f * 64 + lane) * 8);
                acc[0][ni] = __builtin_amdgcn_mfma_f32_16x16x32_bf16(a0, b, acc[0][ni], 0, 0, 0);
                acc[1][ni] = __builtin_amdgcn_mfma_f32_16x16x32_bf16(a1, b, acc[1][ni], 0, 0, 0);
            }
        }
#pragma unroll
        for (int mi = 0; mi < 2; mi++)
#pragma unroll
            for (int ni = 0; ni < 2; ni++) {
                int col = wn * 32 + ni * 16 + lr;
                float bv = b2b[col];
#pragma unroll
                for (int r = 0; r < 4; r++) {
                    int row = wm * 32 + mi * 16 + rbase + r;
                    int ob  = o0 + row;
                    if (ob < obj_hi) {
                        float v = acc[mi][ni][r] + bv;
                        v = v > 0.f ? v : 0.f;
                        out_obj[(size_t)ob * DOUTD + col] = v;
                    }
                }
            }
    }
}

// ---------------- launch ----------------
extern "C" void kernel_launch(void* const* d_in, const int* in_sizes, int n_in,
                              void* d_out, int out_size, void* d_ws, size_t ws_size,
                              hipStream_t stream)
{
    const float* obj   = (const float*)d_in[0];
    const float* pred  = (const float*)d_in[1];
    const int*   edges = (const int*)d_in[2];
    const float* W1a = (const float*)d_in[3];
    const float* b1a = (const float*)d_in[4];
    const float* W1b = (const float*)d_in[5];
    const float* b1b = (const float*)d_in[6];
    const float* W2a = (const float*)d_in[7];
    const float* b2a = (const float*)d_in[8];
    const float* W2b = (const float*)d_in[9];
    const float* b2b = (const float*)d_in[10];

    float* out_obj = (float*)d_out;                       // f32 outputs (reference dtype)
    float* out_p   = (float*)d_out + (size_t)NOBJ * DOUTD;

    // ws layout (bytes):
    // [0, 800000)        sidx      [800000, 1600000)  oidx
    // [1600000, 1800000) counts    [1800000, 1800004) flag
    // [1800064, 4028288) packed weights
    // [4028416, ...)     pooled chunk (f32, rows_per * 512)
    char* ws = (char*)d_ws;
    int*    sidx   = (int*)ws;
    int*    oidx   = sidx + NTRI;
    float*  counts = (float*)(ws + 1600000);
    int*    flag   = (int*)(ws + 1800000);
    __bf16* pW1a   = (__bf16*)(ws + 1800064);            // 196608 elems
    __bf16* pW1b   = pW1a + 196608;                      // 589824 elems
    __bf16* pW2a   = pW1b + 589824;                      // 262144 elems
    __bf16* pW2b   = pW2a + 262144;                      // 65536 elems
    float*  pooled = (float*)(ws + 4028416);

    int npass;
    if      (ws_size >= (size_t)4028416 + 102400000) npass = 1;
    else if (ws_size >= (size_t)4028416 + 51200000)  npass = 2;
    else if (ws_size >= (size_t)4028416 + 25600000)  npass = 4;
    else                                             npass = 8;
    int rows_per = NOBJ / npass;

    hipMemsetAsync(counts, 0, 200064, stream);           // counts + flag

    detect_i64<<<(NTRI + 255) / 256, 256, 0, stream>>>(edges, flag);
    normalize_edges<<<(NTRI + 255) / 256, 256, 0, stream>>>(edges, flag, sidx, oidx);

    pack_w<<<(24576 + 255) / 256, 256, 0, stream>>>(W1a, pW1a, 384, 512);
    pack_w<<<(73728 + 255) / 256, 256, 0, stream>>>(W1b, pW1b, 512, 1152);
    pack_w<<<(32768 + 255) / 256, 256, 0, stream>>>(W2a, pW2a, 512, 512);
    pack_w<<<(8192  + 255) / 256, 256, 0, stream>>>(W2b, pW2b, 512, 128);

    count_k<<<(NTRI + 255) / 256, 256, 0, stream>>>(sidx, oidx, counts);

    size_t lds12 = (size_t)64 * SA_STRIDE * 2 + (size_t)64 * SH_STRIDE * 2;  // 116736
    size_t lds34 = (size_t)2 * 64 * SH_STRIDE * 2;                           // 133120

    for (int p = 0; p < npass; ++p) {
        int lo = p * rows_per, hi = lo + rows_per;
        hipMemsetAsync(pooled, 0, (size_t)rows_per * HD * 4, stream);
        fused12<<<NTRI / TM, 512, lds12, stream>>>(obj, pred, sidx, oidx,
                                                   pW1a, b1a, pW1b, b1b,
                                                   pooled, out_p, lo, hi, p == 0 ? 1 : 0);
        fused34<<<(rows_per + TM - 1) / TM, 512, lds34, stream>>>(pooled, counts,
                                                                  pW2a, b2a, pW2b, b2b,
                                                                  out_obj, lo, hi);
    }
}

// Round 7
// 1849.506 us; speedup vs baseline: 1.1257x; 1.1257x over previous
//
#include <hip/hip_runtime.h>
#include <hip/hip_bf16.h>
#include <stdint.h>

typedef __bf16 bf16x8 __attribute__((ext_vector_type(8)));
typedef __bf16 bf16x4 __attribute__((ext_vector_type(4)));
typedef float  f32x4  __attribute__((ext_vector_type(4)));

#define DIN   128
#define KA    384
#define HD    512
#define NB    1152
#define DOUTD 128
#define NOBJ  50000
#define NTRI  200000
#define TM    64
#define NSCAN 98   // ceil(NOBJ/512)

// ---------------- edges normalization (int32/int64 auto-detect, clamp) ----------------
__global__ void detect_i64(const int* __restrict__ e, int* __restrict__ flag) {
    int i = blockIdx.x * 256 + threadIdx.x;
    if (i < NTRI && e[2 * i + 1] != 0) atomicOr(flag, 1);   // odd words nonzero => int32 layout
}
__global__ void normalize_edges(const int* __restrict__ e, const int* __restrict__ flag,
                                int* __restrict__ sidx, int* __restrict__ oidx) {
    int t = blockIdx.x * 256 + threadIdx.x;
    if (t >= NTRI) return;
    bool is64 = (*flag == 0);
    int s = is64 ? e[4 * t]     : e[2 * t];
    int o = is64 ? e[4 * t + 2] : e[2 * t + 1];
    s = s < 0 ? 0 : (s >= NOBJ ? NOBJ - 1 : s);
    o = o < 0 ? 0 : (o >= NOBJ ? NOBJ - 1 : o);
    sidx[t] = s; oidx[t] = o;
}

// ---------------- weight packing: f32 row-major (K,N) -> bf16 MFMA B-fragments ----------------
__global__ void pack_w(const float* __restrict__ W, __bf16* __restrict__ P, int K, int N) {
    int idx = blockIdx.x * 256 + threadIdx.x;
    int total = (K / 32) * (N / 16) * 64;
    if (idx >= total) return;
    int lane = idx & 63;
    int f    = idx >> 6;
    int NT   = N / 16;
    int kt = f / NT, nt = f - kt * NT;
    int krow = kt * 32 + (lane >> 4) * 8;
    int col  = nt * 16 + (lane & 15);
    __bf16 tmp[8];
#pragma unroll
    for (int i = 0; i < 8; i++) tmp[i] = (__bf16)W[(size_t)(krow + i) * N + col];
    *reinterpret_cast<bf16x8*>(P + (size_t)idx * 8) = *reinterpret_cast<const bf16x8*>(tmp);
}

// ---------------- degree counts ----------------
__global__ void count_f32(const int* __restrict__ sidx, const int* __restrict__ oidx,
                          float* __restrict__ counts) {
    int t = blockIdx.x * 256 + threadIdx.x;
    if (t >= NTRI) return;
    atomicAdd(&counts[sidx[t]], 1.0f);
    atomicAdd(&counts[oidx[t]], 1.0f);
}
__global__ void count_int(const int* __restrict__ sidx, const int* __restrict__ oidx,
                          int* __restrict__ cnt) {
    int t = blockIdx.x * 256 + threadIdx.x;
    if (t >= NTRI) return;
    atomicAdd(&cnt[sidx[t]], 1);
    atomicAdd(&cnt[oidx[t]], 1);
}

// ---------------- CSR prefix scan (3 kernels) ----------------
__global__ void scanA(const int* __restrict__ cnt, int* __restrict__ sums) {
    __shared__ int sh[512];
    int idx = blockIdx.x * 512 + threadIdx.x;
    sh[threadIdx.x] = idx < NOBJ ? cnt[idx] : 0;
    __syncthreads();
    for (int s = 256; s > 0; s >>= 1) {
        if (threadIdx.x < s) sh[threadIdx.x] += sh[threadIdx.x + s];
        __syncthreads();
    }
    if (threadIdx.x == 0) sums[blockIdx.x] = sh[0];
}
__global__ void scanB(int* __restrict__ sums) {
    if (threadIdx.x == 0) {
        int run = 0;
        for (int i = 0; i < NSCAN; i++) { int v = sums[i]; sums[i] = run; run += v; }
    }
}
__global__ void scanC(const int* __restrict__ cnt, const int* __restrict__ sums,
                      int* __restrict__ offs, int* __restrict__ cursor) {
    __shared__ int sh[512];
    int idx = blockIdx.x * 512 + threadIdx.x;
    int v = idx < NOBJ ? cnt[idx] : 0;
    sh[threadIdx.x] = v;
    __syncthreads();
    for (int d = 1; d < 512; d <<= 1) {
        int t = (threadIdx.x >= d) ? sh[threadIdx.x - d] : 0;
        __syncthreads();
        sh[threadIdx.x] += t;
        __syncthreads();
    }
    if (idx < NOBJ) {
        int excl = sh[threadIdx.x] - v + sums[blockIdx.x];
        offs[idx] = excl; cursor[idx] = excl;
    }
}
__global__ void fill_refs(const int* __restrict__ sidx, const int* __restrict__ oidx,
                          int* __restrict__ cursor, int* __restrict__ refs) {
    int t = blockIdx.x * 256 + threadIdx.x;
    if (t >= NTRI) return;
    int p = atomicAdd(&cursor[sidx[t]], 1); refs[p] = 2 * t;
    int q = atomicAdd(&cursor[oidx[t]], 1); refs[q] = 2 * t + 1;
}

// ---------------- pooling: CSR gather mean -> x (bf16) ----------------
__global__ __launch_bounds__(512) void pool_mean(
    const __bf16* __restrict__ newso, const int* __restrict__ cnt,
    const int* __restrict__ offs, const int* __restrict__ refs,
    __bf16* __restrict__ xbuf)
{
    int w    = (blockIdx.x * 512 + threadIdx.x) >> 6;   // one wave per object
    int lane = threadIdx.x & 63;
    if (w >= NOBJ) return;
    int n = cnt[w], off = offs[w];
    float acc[8];
#pragma unroll
    for (int i = 0; i < 8; i++) acc[i] = 0.f;
    for (int j = 0; j < n; j++) {
        int r = refs[off + j];
        const __bf16* src = newso + (size_t)(r >> 1) * 1024 + (r & 1) * 512 + lane * 8;
        bf16x8 v = *reinterpret_cast<const bf16x8*>(src);
#pragma unroll
        for (int i = 0; i < 8; i++) acc[i] += (float)v[i];
    }
    float inv = 1.f / (n > 0 ? (float)n : 1.f);
    bf16x8 o;
#pragma unroll
    for (int i = 0; i < 8; i++) o[i] = (__bf16)(acc[i] * inv);
    *reinterpret_cast<bf16x8*>(xbuf + (size_t)w * 512 + lane * 8) = o;
}

// ---------------- fused GEMM1 + GEMM2 ----------------
#define SA_STRIDE 392
#define SH_STRIDE 520
template<int FAST>
__global__ __launch_bounds__(512) void fused12(
    const float* __restrict__ obj, const float* __restrict__ pred,
    const int* __restrict__ sidx, const int* __restrict__ oidx,
    const __bf16* __restrict__ pW1a, const float* __restrict__ b1a,
    const __bf16* __restrict__ pW1b, const float* __restrict__ b1b,
    float* __restrict__ pooled, float* __restrict__ out_p,
    __bf16* __restrict__ newso,
    int obj_lo, int obj_hi, int write_p)
{
    extern __shared__ char smem[];
    __bf16* sA = (__bf16*)smem;                          // 64*392*2 = 50176 B
    __bf16* sH = (__bf16*)(smem + 64 * SA_STRIDE * 2);   // 64*520*2 = 66560 B

    const int tid  = threadIdx.x;
    const int lane = tid & 63;
    const int wid  = tid >> 6;
    const int t0   = blockIdx.x * TM;

    // ---- Phase 1: gather cur_t tile (f32 -> bf16) into LDS ----
    for (int u = tid; u < 64 * 96; u += 512) {
        int part = u & 31;
        int seg  = (u >> 5) % 3;
        int row  = u / 96;
        int t    = t0 + row;
        const float* src;
        if (seg == 0)      src = obj  + (size_t)sidx[t] * DIN;
        else if (seg == 1) src = pred + (size_t)t       * DIN;
        else               src = obj  + (size_t)oidx[t] * DIN;
        float4 v = *reinterpret_cast<const float4*>(src + part * 4);
        bf16x4 w;
        w[0] = (__bf16)v.x; w[1] = (__bf16)v.y; w[2] = (__bf16)v.z; w[3] = (__bf16)v.w;
        *reinterpret_cast<bf16x4*>(sA + row * SA_STRIDE + seg * 128 + part * 4) = w;
    }
    __syncthreads();

    const int wm = wid >> 2;
    const int wn = wid & 3;
    const int lk = (lane >> 4) * 8;
    const int lr = lane & 15;
    const int rbase = (lane >> 4) * 4;

    // ---- Phase 2: h = relu(cur_t @ W1a + b1a), 64x512 ----
    {
        f32x4 acc[2][8];
#pragma unroll
        for (int mi = 0; mi < 2; mi++)
#pragma unroll
            for (int ni = 0; ni < 8; ni++) acc[mi][ni] = (f32x4){0.f, 0.f, 0.f, 0.f};

        for (int kt = 0; kt < KA / 32; ++kt) {
            bf16x8 a0 = *reinterpret_cast<const bf16x8*>(sA + (wm * 32 + lr) * SA_STRIDE + kt * 32 + lk);
            bf16x8 a1 = *reinterpret_cast<const bf16x8*>(sA + (wm * 32 + 16 + lr) * SA_STRIDE + kt * 32 + lk);
#pragma unroll
            for (int ni = 0; ni < 8; ni++) {
                int f = kt * 32 + wn * 8 + ni;
                bf16x8 b = *reinterpret_cast<const bf16x8*>(pW1a + ((size_t)f * 64 + lane) * 8);
                acc[0][ni] = __builtin_amdgcn_mfma_f32_16x16x32_bf16(a0, b, acc[0][ni], 0, 0, 0);
                acc[1][ni] = __builtin_amdgcn_mfma_f32_16x16x32_bf16(a1, b, acc[1][ni], 0, 0, 0);
            }
        }
#pragma unroll
        for (int mi = 0; mi < 2; mi++)
#pragma unroll
            for (int ni = 0; ni < 8; ni++) {
                int col = wn * 128 + ni * 16 + lr;
                float bv = b1a[col];
#pragma unroll
                for (int r = 0; r < 4; r++) {
                    float v = acc[mi][ni][r] + bv;
                    v = v > 0.f ? v : 0.f;
                    sH[(wm * 32 + mi * 16 + rbase + r) * SH_STRIDE + col] = (__bf16)v;
                }
            }
    }
    __syncthreads();

    // ---- Phase 3: new_t = relu(h @ W1b + b1b), 64x1152; route ----
    {
        f32x4 acc2[2][18];
#pragma unroll
        for (int mi = 0; mi < 2; mi++)
#pragma unroll
            for (int ni = 0; ni < 18; ni++) acc2[mi][ni] = (f32x4){0.f, 0.f, 0.f, 0.f};

        for (int kt = 0; kt < HD / 32; ++kt) {
            bf16x8 a0 = *reinterpret_cast<const bf16x8*>(sH + (wm * 32 + lr) * SH_STRIDE + kt * 32 + lk);
            bf16x8 a1 = *reinterpret_cast<const bf16x8*>(sH + (wm * 32 + 16 + lr) * SH_STRIDE + kt * 32 + lk);
#pragma unroll
            for (int ni = 0; ni < 18; ni++) {
                int f = kt * 72 + wn * 18 + ni;
                bf16x8 b = *reinterpret_cast<const bf16x8*>(pW1b + ((size_t)f * 64 + lane) * 8);
                acc2[0][ni] = __builtin_amdgcn_mfma_f32_16x16x32_bf16(a0, b, acc2[0][ni], 0, 0, 0);
                acc2[1][ni] = __builtin_amdgcn_mfma_f32_16x16x32_bf16(a1, b, acc2[1][ni], 0, 0, 0);
            }
        }
#pragma unroll
        for (int mi = 0; mi < 2; mi++) {
#pragma unroll
            for (int r = 0; r < 4; r++) {
                int row = wm * 32 + mi * 16 + rbase + r;
                int t   = t0 + row;
                int si  = sidx[t];
                int oi  = oidx[t];
#pragma unroll
                for (int ni = 0; ni < 18; ni++) {
                    int c = wn * 288 + ni * 16 + lr;
                    float v = acc2[mi][ni][r] + b1b[c];
                    v = v > 0.f ? v : 0.f;
                    if constexpr (FAST) {
                        if (c < HD) {
                            newso[(size_t)t * 1024 + c] = (__bf16)v;
                        } else if (c < HD + DOUTD) {
                            out_p[(size_t)t * DOUTD + (c - HD)] = v;
                        } else {
                            newso[(size_t)t * 1024 + 512 + (c - HD - DOUTD)] = (__bf16)v;
                        }
                    } else {
                        if (c < HD) {
                            if (si >= obj_lo && si < obj_hi)
                                atomicAdd(pooled + (size_t)(si - obj_lo) * HD + c, v);
                        } else if (c < HD + DOUTD) {
                            if (write_p)
                                out_p[(size_t)t * DOUTD + (c - HD)] = v;
                        } else {
                            if (oi >= obj_lo && oi < obj_hi)
                                atomicAdd(pooled + (size_t)(oi - obj_lo) * HD + (c - HD - DOUTD), v);
                        }
                    }
                }
            }
        }
    }
}

// ---------------- fused GEMM3 + GEMM4 ----------------
template<int FAST>
__global__ __launch_bounds__(512) void fused34(
    const float* __restrict__ pooled, const float* __restrict__ counts,
    const __bf16* __restrict__ xbuf,
    const __bf16* __restrict__ pW2a, const float* __restrict__ b2a,
    const __bf16* __restrict__ pW2b, const float* __restrict__ b2b,
    float* __restrict__ out_obj, int obj_lo, int obj_hi)
{
    extern __shared__ char smem[];
    __bf16* sX  = (__bf16*)smem;
    __bf16* sH2 = (__bf16*)(smem + 64 * SH_STRIDE * 2);

    const int tid  = threadIdx.x;
    const int lane = tid & 63;
    const int wid  = tid >> 6;
    const int o0   = obj_lo + blockIdx.x * TM;

    // ---- Phase 1: x tile -> LDS (bf16) ----
    if constexpr (FAST) {
        for (int u = tid; u < 64 * 64; u += 512) {       // 64 rows x 64 parts (8 bf16)
            int part = u & 63;
            int row  = u >> 6;
            int ob   = o0 + row;
            bf16x8 v;
            if (ob < obj_hi) v = *reinterpret_cast<const bf16x8*>(xbuf + (size_t)ob * 512 + part * 8);
            else { bf16x8 z = {}; v = z; }
            *reinterpret_cast<bf16x8*>(sX + row * SH_STRIDE + part * 8) = v;
        }
    } else {
        for (int u = tid; u < 64 * 128; u += 512) {
            int part = u & 127;
            int row  = u >> 7;
            int ob   = o0 + row;
            float4 v = {0.f, 0.f, 0.f, 0.f};
            float inv = 1.f;
            if (ob < obj_hi) {
                v = *reinterpret_cast<const float4*>(pooled + (size_t)(ob - obj_lo) * HD + part * 4);
                float c = counts[ob];
                inv = 1.f / (c > 1.f ? c : 1.f);
            }
            bf16x4 w;
            w[0] = (__bf16)(v.x * inv); w[1] = (__bf16)(v.y * inv);
            w[2] = (__bf16)(v.z * inv); w[3] = (__bf16)(v.w * inv);
            *reinterpret_cast<bf16x4*>(sX + row * SH_STRIDE + part * 4) = w;
        }
    }
    __syncthreads();

    const int wm = wid >> 2;
    const int wn = wid & 3;
    const int lk = (lane >> 4) * 8;
    const int lr = lane & 15;
    const int rbase = (lane >> 4) * 4;

    // ---- Phase 2: h2 = relu(x @ W2a + b2a), 64x512 ----
    {
        f32x4 acc[2][8];
#pragma unroll
        for (int mi = 0; mi < 2; mi++)
#pragma unroll
            for (int ni = 0; ni < 8; ni++) acc[mi][ni] = (f32x4){0.f, 0.f, 0.f, 0.f};

        for (int kt = 0; kt < HD / 32; ++kt) {
            bf16x8 a0 = *reinterpret_cast<const bf16x8*>(sX + (wm * 32 + lr) * SH_STRIDE + kt * 32 + lk);
            bf16x8 a1 = *reinterpret_cast<const bf16x8*>(sX + (wm * 32 + 16 + lr) * SH_STRIDE + kt * 32 + lk);
#pragma unroll
            for (int ni = 0; ni < 8; ni++) {
                int f = kt * 32 + wn * 8 + ni;
                bf16x8 b = *reinterpret_cast<const bf16x8*>(pW2a + ((size_t)f * 64 + lane) * 8);
                acc[0][ni] = __builtin_amdgcn_mfma_f32_16x16x32_bf16(a0, b, acc[0][ni], 0, 0, 0);
                acc[1][ni] = __builtin_amdgcn_mfma_f32_16x16x32_bf16(a1, b, acc[1][ni], 0, 0, 0);
            }
        }
#pragma unroll
        for (int mi = 0; mi < 2; mi++)
#pragma unroll
            for (int ni = 0; ni < 8; ni++) {
                int col = wn * 128 + ni * 16 + lr;
                float bv = b2a[col];
#pragma unroll
                for (int r = 0; r < 4; r++) {
                    float v = acc[mi][ni][r] + bv;
                    v = v > 0.f ? v : 0.f;
                    sH2[(wm * 32 + mi * 16 + rbase + r) * SH_STRIDE + col] = (__bf16)v;
                }
            }
    }
    __syncthreads();

    // ---- Phase 3: new_obj = relu(h2 @ W2b + b2b), 64x128 ----
    {
        f32x4 acc[2][2];
#pragma unroll
        for (int mi = 0; mi < 2; mi++)
#pragma unroll
            for (int ni = 0; ni < 2; ni++) acc[mi][ni] = (f32x4){0.f, 0.f, 0.f, 0.f};

        for (int kt = 0; kt < HD / 32; ++kt) {
            bf16x8 a0 = *reinterpret_cast<const bf16x8*>(sH2 + (wm * 32 + lr) * SH_STRIDE + kt * 32 + lk);
            bf16x8 a1 = *reinterpret_cast<const bf16x8*>(sH2 + (wm * 32 + 16 + lr) * SH_STRIDE + kt * 32 + lk);
#pragma unroll
            for (int ni = 0; ni < 2; ni++) {
                int f = kt * 8 + wn * 2 + ni;
                bf16x8 b = *reinterpret_cast<const bf16x8*>(pW2b + ((size_t)f * 64 + lane) * 8);
                acc[0][ni] = __builtin_amdgcn_mfma_f32_16x16x32_bf16(a0, b, acc[0][ni], 0, 0, 0);
                acc[1][ni] = __builtin_amdgcn_mfma_f32_16x16x32_bf16(a1, b, acc[1][ni], 0, 0, 0);
            }
        }
#pragma unroll
        for (int mi = 0; mi < 2; mi++)
#pragma unroll
            for (int ni = 0; ni < 2; ni++) {
                int col = wn * 32 + ni * 16 + lr;
                float bv = b2b[col];
#pragma unroll
                for (int r = 0; r < 4; r++) {
                    int row = wm * 32 + mi * 16 + rbase + r;
                    int ob  = o0 + row;
                    if (ob < obj_hi) {
                        float v = acc[mi][ni][r] + bv;
                        v = v > 0.f ? v : 0.f;
                        out_obj[(size_t)ob * DOUTD + col] = v;
                    }
                }
            }
    }
}

// ---------------- launch ----------------
extern "C" void kernel_launch(void* const* d_in, const int* in_sizes, int n_in,
                              void* d_out, int out_size, void* d_ws, size_t ws_size,
                              hipStream_t stream)
{
    const float* obj   = (const float*)d_in[0];
    const float* pred  = (const float*)d_in[1];
    const int*   edges = (const int*)d_in[2];
    const float* W1a = (const float*)d_in[3];
    const float* b1a = (const float*)d_in[4];
    const float* W1b = (const float*)d_in[5];
    const float* b1b = (const float*)d_in[6];
    const float* W2a = (const float*)d_in[7];
    const float* b2a = (const float*)d_in[8];
    const float* W2b = (const float*)d_in[9];
    const float* b2b = (const float*)d_in[10];

    float* out_obj = (float*)d_out;
    float* out_p   = (float*)d_out + (size_t)NOBJ * DOUTD;

    // ---- shared/legacy ws layout (bytes) ----
    // [0,800000) sidx  [800000,1600000) oidx  [1600000,1800000) countsF (legacy)
    // [1800000,1800004) flag  [1800064,4028288) packed W  [4028416,...) legacy pooled
    char* ws = (char*)d_ws;
    int*    sidx    = (int*)ws;
    int*    oidx    = sidx + NTRI;
    float*  countsF = (float*)(ws + 1600000);
    int*    flag    = (int*)(ws + 1800000);
    __bf16* pW1a    = (__bf16*)(ws + 1800064);
    __bf16* pW1b    = pW1a + 196608;
    __bf16* pW2a    = pW1b + 589824;
    __bf16* pW2b    = pW2a + 262144;
    float*  pooled  = (float*)(ws + 4028416);

    // ---- fast-path extras (overlay legacy pooled region) ----
    int*    cnt    = (int*)(ws + 4028416);               // 200000
    int*    offs   = (int*)(ws + 4228416);               // 200000
    int*    cursor = (int*)(ws + 4428416);               // 200000
    int*    sums   = (int*)(ws + 4628416);               // 512
    int*    refs   = (int*)(ws + 4628928);               // 1600000
    __bf16* xbuf   = (__bf16*)(ws + 6228928);            // 51200000
    __bf16* newso  = (__bf16*)(ws + 57428928);           // 409600000
    const size_t FAST_NEED = 467028928;

    bool fast = ws_size >= FAST_NEED;

    size_t lds12 = (size_t)64 * SA_STRIDE * 2 + (size_t)64 * SH_STRIDE * 2;  // 116736
    size_t lds34 = (size_t)2 * 64 * SH_STRIDE * 2;                           // 133120

    hipMemsetAsync(flag, 0, 4, stream);
    detect_i64<<<(NTRI + 255) / 256, 256, 0, stream>>>(edges, flag);
    normalize_edges<<<(NTRI + 255) / 256, 256, 0, stream>>>(edges, flag, sidx, oidx);

    pack_w<<<(24576 + 255) / 256, 256, 0, stream>>>(W1a, pW1a, 384, 512);
    pack_w<<<(73728 + 255) / 256, 256, 0, stream>>>(W1b, pW1b, 512, 1152);
    pack_w<<<(32768 + 255) / 256, 256, 0, stream>>>(W2a, pW2a, 512, 512);
    pack_w<<<(8192  + 255) / 256, 256, 0, stream>>>(W2b, pW2b, 512, 128);

    if (fast) {
        // CSR build
        hipMemsetAsync(cnt, 0, 200000, stream);
        count_int<<<(NTRI + 255) / 256, 256, 0, stream>>>(sidx, oidx, cnt);
        scanA<<<NSCAN, 512, 0, stream>>>(cnt, sums);
        scanB<<<1, 64, 0, stream>>>(sums);
        scanC<<<NSCAN, 512, 0, stream>>>(cnt, sums, offs, cursor);
        fill_refs<<<(NTRI + 255) / 256, 256, 0, stream>>>(sidx, oidx, cursor, refs);

        // GEMM1+2, streaming writes
        fused12<1><<<NTRI / TM, 512, lds12, stream>>>(obj, pred, sidx, oidx,
                                                      pW1a, b1a, pW1b, b1b,
                                                      nullptr, out_p, newso, 0, NOBJ, 1);
        // segment mean
        pool_mean<<<(NOBJ * 64 + 511) / 512, 512, 0, stream>>>(newso, cnt, offs, refs, xbuf);
        // GEMM3+4
        fused34<1><<<(NOBJ + TM - 1) / TM, 512, lds34, stream>>>(nullptr, nullptr, xbuf,
                                                                 pW2a, b2a, pW2b, b2b,
                                                                 out_obj, 0, NOBJ);
    } else {
        int npass;
        if      (ws_size >= (size_t)4028416 + 102400000) npass = 1;
        else if (ws_size >= (size_t)4028416 + 51200000)  npass = 2;
        else if (ws_size >= (size_t)4028416 + 25600000)  npass = 4;
        else                                             npass = 8;
        int rows_per = NOBJ / npass;

        hipMemsetAsync(countsF, 0, 200000, stream);
        count_f32<<<(NTRI + 255) / 256, 256, 0, stream>>>(sidx, oidx, countsF);

        for (int p = 0; p < npass; ++p) {
            int lo = p * rows_per, hi = lo + rows_per;
            hipMemsetAsync(pooled, 0, (size_t)rows_per * HD * 4, stream);
            fused12<0><<<NTRI / TM, 512, lds12, stream>>>(obj, pred, sidx, oidx,
                                                          pW1a, b1a, pW1b, b1b,
                                                          pooled, out_p, nullptr, lo, hi, p == 0 ? 1 : 0);
            fused34<0><<<(rows_per + TM - 1) / TM, 512, lds34, stream>>>(pooled, countsF, nullptr,
                                                                         pW2a, b2a, pW2b, b2b,
                                                                         out_obj, lo, hi);
        }
    }
}

// Round 8
// 1075.061 us; speedup vs baseline: 1.9367x; 1.7204x over previous
//
#include <hip/hip_runtime.h>
#include <hip/hip_bf16.h>
#include <stdint.h>

typedef __bf16 bf16x8 __attribute__((ext_vector_type(8)));
typedef __bf16 bf16x4 __attribute__((ext_vector_type(4)));
typedef float  f32x4  __attribute__((ext_vector_type(4)));

#define DIN   128
#define KA    384
#define HD    512
#define NB    1152
#define DOUTD 128
#define NOBJ  50000
#define NTRI  200000
#define TM    64
#define NSCAN 98   // ceil(NOBJ/512)
#define SB_STRIDE 520

// ---------------- edges normalization (int32/int64 auto-detect, clamp) ----------------
__global__ void detect_i64(const int* __restrict__ e, int* __restrict__ flag) {
    int i = blockIdx.x * 256 + threadIdx.x;
    if (i < NTRI && e[2 * i + 1] != 0) atomicOr(flag, 1);   // odd words nonzero => int32 layout
}
__global__ void normalize_edges(const int* __restrict__ e, const int* __restrict__ flag,
                                int* __restrict__ sidx, int* __restrict__ oidx) {
    int t = blockIdx.x * 256 + threadIdx.x;
    if (t >= NTRI) return;
    bool is64 = (*flag == 0);
    int s = is64 ? e[4 * t]     : e[2 * t];
    int o = is64 ? e[4 * t + 2] : e[2 * t + 1];
    s = s < 0 ? 0 : (s >= NOBJ ? NOBJ - 1 : s);
    o = o < 0 ? 0 : (o >= NOBJ ? NOBJ - 1 : o);
    sidx[t] = s; oidx[t] = o;
}

// ---------------- weight packing: f32 row-major (K,N) -> bf16 MFMA B-fragments ----------------
// frag f = kt*(N/16) + nt ; lane l holds W[kt*32 + (l>>4)*8 + i][nt*16 + (l&15)], i=0..7
__global__ void pack_w(const float* __restrict__ W, __bf16* __restrict__ P, int K, int N) {
    int idx = blockIdx.x * 256 + threadIdx.x;
    int total = (K / 32) * (N / 16) * 64;
    if (idx >= total) return;
    int lane = idx & 63;
    int f    = idx >> 6;
    int NT   = N / 16;
    int kt = f / NT, nt = f - kt * NT;
    int krow = kt * 32 + (lane >> 4) * 8;
    int col  = nt * 16 + (lane & 15);
    __bf16 tmp[8];
#pragma unroll
    for (int i = 0; i < 8; i++) tmp[i] = (__bf16)W[(size_t)(krow + i) * N + col];
    *reinterpret_cast<bf16x8*>(P + (size_t)idx * 8) = *reinterpret_cast<const bf16x8*>(tmp);
}

// ---------------- degree counts ----------------
__global__ void count_int(const int* __restrict__ sidx, const int* __restrict__ oidx,
                          int* __restrict__ cnt) {
    int t = blockIdx.x * 256 + threadIdx.x;
    if (t >= NTRI) return;
    atomicAdd(&cnt[sidx[t]], 1);
    atomicAdd(&cnt[oidx[t]], 1);
}

// ---------------- CSR prefix scan (3 kernels) ----------------
__global__ void scanA(const int* __restrict__ cnt, int* __restrict__ sums) {
    __shared__ int sh[512];
    int idx = blockIdx.x * 512 + threadIdx.x;
    sh[threadIdx.x] = idx < NOBJ ? cnt[idx] : 0;
    __syncthreads();
    for (int s = 256; s > 0; s >>= 1) {
        if (threadIdx.x < s) sh[threadIdx.x] += sh[threadIdx.x + s];
        __syncthreads();
    }
    if (threadIdx.x == 0) sums[blockIdx.x] = sh[0];
}
__global__ void scanB(int* __restrict__ sums) {
    if (threadIdx.x == 0) {
        int run = 0;
        for (int i = 0; i < NSCAN; i++) { int v = sums[i]; sums[i] = run; run += v; }
    }
}
__global__ void scanC(const int* __restrict__ cnt, const int* __restrict__ sums,
                      int* __restrict__ offs, int* __restrict__ cursor) {
    __shared__ int sh[512];
    int idx = blockIdx.x * 512 + threadIdx.x;
    int v = idx < NOBJ ? cnt[idx] : 0;
    sh[threadIdx.x] = v;
    __syncthreads();
    for (int d = 1; d < 512; d <<= 1) {
        int t = (threadIdx.x >= d) ? sh[threadIdx.x - d] : 0;
        __syncthreads();
        sh[threadIdx.x] += t;
        __syncthreads();
    }
    if (idx < NOBJ) {
        int excl = sh[threadIdx.x] - v + sums[blockIdx.x];
        offs[idx] = excl; cursor[idx] = excl;
    }
}
__global__ void fill_refs(const int* __restrict__ sidx, const int* __restrict__ oidx,
                          int* __restrict__ cursor, int* __restrict__ refs) {
    int t = blockIdx.x * 256 + threadIdx.x;
    if (t >= NTRI) return;
    int p = atomicAdd(&cursor[sidx[t]], 1); refs[p] = 2 * t;
    int q = atomicAdd(&cursor[oidx[t]], 1); refs[q] = 2 * t + 1;
}

// ---------------- pooling: CSR gather mean -> x (bf16) ----------------
__global__ __launch_bounds__(512) void pool_mean(
    const __bf16* __restrict__ newso, const int* __restrict__ cnt,
    const int* __restrict__ offs, const int* __restrict__ refs,
    __bf16* __restrict__ xbuf)
{
    int w    = (blockIdx.x * 512 + threadIdx.x) >> 6;   // one wave per object
    int lane = threadIdx.x & 63;
    if (w >= NOBJ) return;
    int n = cnt[w], off = offs[w];
    float acc[8];
#pragma unroll
    for (int i = 0; i < 8; i++) acc[i] = 0.f;
    for (int j = 0; j < n; j++) {
        int r = refs[off + j];
        const __bf16* src = newso + (size_t)(r >> 1) * 1024 + (r & 1) * 512 + lane * 8;
        bf16x8 v = *reinterpret_cast<const bf16x8*>(src);
#pragma unroll
        for (int i = 0; i < 8; i++) acc[i] += (float)v[i];
    }
    float inv = 1.f / (n > 0 ? (float)n : 1.f);
    bf16x8 o;
#pragma unroll
    for (int i = 0; i < 8; i++) o[i] = (__bf16)(acc[i] * inv);
    *reinterpret_cast<bf16x8*>(xbuf + (size_t)w * 512 + lane * 8) = o;
}

// ---------------- fused GEMM1 + GEMM2 (1m x 8n waves, aliased LDS, reg-dieted) ----------------
// LDS: one 64x520 bf16 buffer. Phase 1: cur_t tile (cols 0..383).
// GEMM1 accumulates in regs; barrier; h (relu) overwrites the same buffer (cols 0..511).
// GEMM2: 3 N-passes of 3 n-tiles/wave; epilogue routes to newso / out_p.
__global__ __launch_bounds__(512, 4) void fused12(
    const float* __restrict__ obj, const float* __restrict__ pred,
    const int* __restrict__ sidx, const int* __restrict__ oidx,
    const __bf16* __restrict__ pW1a, const float* __restrict__ b1a,
    const __bf16* __restrict__ pW1b, const float* __restrict__ b1b,
    float* __restrict__ out_p, __bf16* __restrict__ newso)
{
    extern __shared__ char smem[];
    __bf16* sB = (__bf16*)smem;                          // 64*520*2 = 66560 B

    const int tid  = threadIdx.x;
    const int lane = tid & 63;
    const int wn   = tid >> 6;          // 0..7 : N-slice owner
    const int t0   = blockIdx.x * TM;

    const int lk    = (lane >> 4) * 8;  // K sub-offset within 32
    const int lr    = lane & 15;        // A-row / B-col / D-col
    const int rbase = (lane >> 4) * 4;  // D row base

    // ---- Phase 1: gather cur_t tile (f32 -> bf16) into LDS ----
    for (int u = tid; u < 64 * 96; u += 512) {
        int part = u & 31;
        int seg  = (u >> 5) % 3;
        int row  = u / 96;
        int t    = t0 + row;
        const float* src;
        if (seg == 0)      src = obj  + (size_t)sidx[t] * DIN;
        else if (seg == 1) src = pred + (size_t)t       * DIN;
        else               src = obj  + (size_t)oidx[t] * DIN;
        float4 v = *reinterpret_cast<const float4*>(src + part * 4);
        bf16x4 w;
        w[0] = (__bf16)v.x; w[1] = (__bf16)v.y; w[2] = (__bf16)v.z; w[3] = (__bf16)v.w;
        *reinterpret_cast<bf16x4*>(sB + row * SB_STRIDE + seg * 128 + part * 4) = w;
    }
    __syncthreads();

    // ---- GEMM1: h = relu(cur_t @ W1a + b1a); wave covers 64 rows x 64 cols ----
    {
        f32x4 acc[4][4];
#pragma unroll
        for (int mi = 0; mi < 4; mi++)
#pragma unroll
            for (int ni = 0; ni < 4; ni++) acc[mi][ni] = (f32x4){0.f, 0.f, 0.f, 0.f};

        for (int kt = 0; kt < KA / 32; ++kt) {
            bf16x8 a[4];
#pragma unroll
            for (int mi = 0; mi < 4; mi++)
                a[mi] = *reinterpret_cast<const bf16x8*>(sB + (mi * 16 + lr) * SB_STRIDE + kt * 32 + lk);
#pragma unroll
            for (int ni = 0; ni < 4; ni++) {
                int f = kt * 32 + wn * 4 + ni;            // NT = 512/16 = 32
                bf16x8 b = *reinterpret_cast<const bf16x8*>(pW1a + ((size_t)f * 64 + lane) * 8);
#pragma unroll
                for (int mi = 0; mi < 4; mi++)
                    acc[mi][ni] = __builtin_amdgcn_mfma_f32_16x16x32_bf16(a[mi], b, acc[mi][ni], 0, 0, 0);
            }
        }
        __syncthreads();    // all cur_t reads complete before h overwrites the buffer

        // epilogue: bias + relu -> sB (h, bf16)
#pragma unroll
        for (int ni = 0; ni < 4; ni++) {
            int col = wn * 64 + ni * 16 + lr;
            float bv = b1a[col];
#pragma unroll
            for (int mi = 0; mi < 4; mi++)
#pragma unroll
                for (int r = 0; r < 4; r++) {
                    float v = acc[mi][ni][r] + bv;
                    v = v > 0.f ? v : 0.f;
                    sB[(mi * 16 + rbase + r) * SB_STRIDE + col] = (__bf16)v;
                }
        }
    }
    __syncthreads();

    // ---- GEMM2: new_t = relu(h @ W1b + b1b); wave covers 64 rows x 144 cols, 3 passes ----
    for (int pp = 0; pp < 3; ++pp) {
        f32x4 acc2[4][3];
#pragma unroll
        for (int mi = 0; mi < 4; mi++)
#pragma unroll
            for (int ni = 0; ni < 3; ni++) acc2[mi][ni] = (f32x4){0.f, 0.f, 0.f, 0.f};

        for (int kt = 0; kt < HD / 32; ++kt) {
            bf16x8 a[4];
#pragma unroll
            for (int mi = 0; mi < 4; mi++)
                a[mi] = *reinterpret_cast<const bf16x8*>(sB + (mi * 16 + lr) * SB_STRIDE + kt * 32 + lk);
#pragma unroll
            for (int ni = 0; ni < 3; ni++) {
                int f = kt * 72 + wn * 9 + pp * 3 + ni;   // NT = 1152/16 = 72
                bf16x8 b = *reinterpret_cast<const bf16x8*>(pW1b + ((size_t)f * 64 + lane) * 8);
#pragma unroll
                for (int mi = 0; mi < 4; mi++)
                    acc2[mi][ni] = __builtin_amdgcn_mfma_f32_16x16x32_bf16(a[mi], b, acc2[mi][ni], 0, 0, 0);
            }
        }
        // epilogue: bias + relu, route (no barrier needed: only global writes)
#pragma unroll
        for (int ni = 0; ni < 3; ni++) {
            int c = wn * 144 + pp * 48 + ni * 16 + lr;
            float bv = b1b[c];
#pragma unroll
            for (int mi = 0; mi < 4; mi++)
#pragma unroll
                for (int r = 0; r < 4; r++) {
                    int row = mi * 16 + rbase + r;
                    int t   = t0 + row;
                    float v = acc2[mi][ni][r] + bv;
                    v = v > 0.f ? v : 0.f;
                    if (c < HD) {
                        newso[(size_t)t * 1024 + c] = (__bf16)v;
                    } else if (c < HD + DOUTD) {
                        out_p[(size_t)t * DOUTD + (c - HD)] = v;
                    } else {
                        newso[(size_t)t * 1024 + 512 + (c - HD - DOUTD)] = (__bf16)v;
                    }
                }
        }
    }
}

// ---------------- fused GEMM3 + GEMM4 ----------------
#define SH_STRIDE 520
__global__ __launch_bounds__(512) void fused34(
    const __bf16* __restrict__ xbuf,
    const __bf16* __restrict__ pW2a, const float* __restrict__ b2a,
    const __bf16* __restrict__ pW2b, const float* __restrict__ b2b,
    float* __restrict__ out_obj)
{
    extern __shared__ char smem[];
    __bf16* sX  = (__bf16*)smem;
    __bf16* sH2 = (__bf16*)(smem + 64 * SH_STRIDE * 2);

    const int tid  = threadIdx.x;
    const int lane = tid & 63;
    const int wid  = tid >> 6;
    const int o0   = blockIdx.x * TM;

    // ---- Phase 1: x tile -> LDS (bf16) ----
    for (int u = tid; u < 64 * 64; u += 512) {           // 64 rows x 64 parts (8 bf16)
        int part = u & 63;
        int row  = u >> 6;
        int ob   = o0 + row;
        bf16x8 v;
        if (ob < NOBJ) v = *reinterpret_cast<const bf16x8*>(xbuf + (size_t)ob * 512 + part * 8);
        else { bf16x8 z = {}; v = z; }
        *reinterpret_cast<bf16x8*>(sX + row * SH_STRIDE + part * 8) = v;
    }
    __syncthreads();

    const int wm = wid >> 2;
    const int wn = wid & 3;
    const int lk = (lane >> 4) * 8;
    const int lr = lane & 15;
    const int rbase = (lane >> 4) * 4;

    // ---- Phase 2: h2 = relu(x @ W2a + b2a), 64x512 ----
    {
        f32x4 acc[2][8];
#pragma unroll
        for (int mi = 0; mi < 2; mi++)
#pragma unroll
            for (int ni = 0; ni < 8; ni++) acc[mi][ni] = (f32x4){0.f, 0.f, 0.f, 0.f};

        for (int kt = 0; kt < HD / 32; ++kt) {
            bf16x8 a0 = *reinterpret_cast<const bf16x8*>(sX + (wm * 32 + lr) * SH_STRIDE + kt * 32 + lk);
            bf16x8 a1 = *reinterpret_cast<const bf16x8*>(sX + (wm * 32 + 16 + lr) * SH_STRIDE + kt * 32 + lk);
#pragma unroll
            for (int ni = 0; ni < 8; ni++) {
                int f = kt * 32 + wn * 8 + ni;
                bf16x8 b = *reinterpret_cast<const bf16x8*>(pW2a + ((size_t)f * 64 + lane) * 8);
                acc[0][ni] = __builtin_amdgcn_mfma_f32_16x16x32_bf16(a0, b, acc[0][ni], 0, 0, 0);
                acc[1][ni] = __builtin_amdgcn_mfma_f32_16x16x32_bf16(a1, b, acc[1][ni], 0, 0, 0);
            }
        }
#pragma unroll
        for (int mi = 0; mi < 2; mi++)
#pragma unroll
            for (int ni = 0; ni < 8; ni++) {
                int col = wn * 128 + ni * 16 + lr;
                float bv = b2a[col];
#pragma unroll
                for (int r = 0; r < 4; r++) {
                    float v = acc[mi][ni][r] + bv;
                    v = v > 0.f ? v : 0.f;
                    sH2[(wm * 32 + mi * 16 + rbase + r) * SH_STRIDE + col] = (__bf16)v;
                }
            }
    }
    __syncthreads();

    // ---- Phase 3: new_obj = relu(h2 @ W2b + b2b), 64x128 ----
    {
        f32x4 acc[2][2];
#pragma unroll
        for (int mi = 0; mi < 2; mi++)
#pragma unroll
            for (int ni = 0; ni < 2; ni++) acc[mi][ni] = (f32x4){0.f, 0.f, 0.f, 0.f};

        for (int kt = 0; kt < HD / 32; ++kt) {
            bf16x8 a0 = *reinterpret_cast<const bf16x8*>(sH2 + (wm * 32 + lr) * SH_STRIDE + kt * 32 + lk);
            bf16x8 a1 = *reinterpret_cast<const bf16x8*>(sH2 + (wm * 32 + 16 + lr) * SH_STRIDE + kt * 32 + lk);
#pragma unroll
            for (int ni = 0; ni < 2; ni++) {
                int f = kt * 8 + wn * 2 + ni;
                bf16x8 b = *reinterpret_cast<const bf16x8*>(pW2b + ((size_t)f * 64 + lane) * 8);
                acc[0][ni] = __builtin_amdgcn_mfma_f32_16x16x32_bf16(a0, b, acc[0][ni], 0, 0, 0);
                acc[1][ni] = __builtin_amdgcn_mfma_f32_16x16x32_bf16(a1, b, acc[1][ni], 0, 0, 0);
            }
        }
#pragma unroll
        for (int mi = 0; mi < 2; mi++)
#pragma unroll
            for (int ni = 0; ni < 2; ni++) {
                int col = wn * 32 + ni * 16 + lr;
                float bv = b2b[col];
#pragma unroll
                for (int r = 0; r < 4; r++) {
                    int row = wm * 32 + mi * 16 + rbase + r;
                    int ob  = o0 + row;
                    if (ob < NOBJ) {
                        float v = acc[mi][ni][r] + bv;
                        v = v > 0.f ? v : 0.f;
                        out_obj[(size_t)ob * DOUTD + col] = v;
                    }
                }
            }
    }
}

// ---------------- launch ----------------
extern "C" void kernel_launch(void* const* d_in, const int* in_sizes, int n_in,
                              void* d_out, int out_size, void* d_ws, size_t ws_size,
                              hipStream_t stream)
{
    const float* obj   = (const float*)d_in[0];
    const float* pred  = (const float*)d_in[1];
    const int*   edges = (const int*)d_in[2];
    const float* W1a = (const float*)d_in[3];
    const float* b1a = (const float*)d_in[4];
    const float* W1b = (const float*)d_in[5];
    const float* b1b = (const float*)d_in[6];
    const float* W2a = (const float*)d_in[7];
    const float* b2a = (const float*)d_in[8];
    const float* W2b = (const float*)d_in[9];
    const float* b2b = (const float*)d_in[10];

    float* out_obj = (float*)d_out;
    float* out_p   = (float*)d_out + (size_t)NOBJ * DOUTD;

    // ws layout (bytes) — proven to fit in R7 (fast path engaged):
    // [0,800000) sidx  [800000,1600000) oidx  [1800000,1800004) flag
    // [1800064,4028288) packed W
    // [4028416,...) cnt/offs/cursor/sums/refs ; xbuf @6228928 ; newso @57428928
    char* ws = (char*)d_ws;
    int*    sidx   = (int*)ws;
    int*    oidx   = sidx + NTRI;
    int*    flag   = (int*)(ws + 1800000);
    __bf16* pW1a   = (__bf16*)(ws + 1800064);
    __bf16* pW1b   = pW1a + 196608;
    __bf16* pW2a   = pW1b + 589824;
    __bf16* pW2b   = pW2a + 262144;
    int*    cnt    = (int*)(ws + 4028416);
    int*    offs   = (int*)(ws + 4228416);
    int*    cursor = (int*)(ws + 4428416);
    int*    sums   = (int*)(ws + 4628416);
    int*    refs   = (int*)(ws + 4628928);
    __bf16* xbuf   = (__bf16*)(ws + 6228928);
    __bf16* newso  = (__bf16*)(ws + 57428928);

    hipMemsetAsync(flag, 0, 4, stream);
    detect_i64<<<(NTRI + 255) / 256, 256, 0, stream>>>(edges, flag);
    normalize_edges<<<(NTRI + 255) / 256, 256, 0, stream>>>(edges, flag, sidx, oidx);

    pack_w<<<(24576 + 255) / 256, 256, 0, stream>>>(W1a, pW1a, 384, 512);
    pack_w<<<(73728 + 255) / 256, 256, 0, stream>>>(W1b, pW1b, 512, 1152);
    pack_w<<<(32768 + 255) / 256, 256, 0, stream>>>(W2a, pW2a, 512, 512);
    pack_w<<<(8192  + 255) / 256, 256, 0, stream>>>(W2b, pW2b, 512, 128);

    // CSR build
    hipMemsetAsync(cnt, 0, 200000, stream);
    count_int<<<(NTRI + 255) / 256, 256, 0, stream>>>(sidx, oidx, cnt);
    scanA<<<NSCAN, 512, 0, stream>>>(cnt, sums);
    scanB<<<1, 64, 0, stream>>>(sums);
    scanC<<<NSCAN, 512, 0, stream>>>(cnt, sums, offs, cursor);
    fill_refs<<<(NTRI + 255) / 256, 256, 0, stream>>>(sidx, oidx, cursor, refs);

    // GEMM1+2 (fused, streaming writes)
    size_t lds12 = (size_t)64 * SB_STRIDE * 2;           // 66560 -> 2 blocks/CU
    fused12<<<NTRI / TM, 512, lds12, stream>>>(obj, pred, sidx, oidx,
                                               pW1a, b1a, pW1b, b1b,
                                               out_p, newso);
    // segment mean
    pool_mean<<<(NOBJ * 64 + 511) / 512, 512, 0, stream>>>(newso, cnt, offs, refs, xbuf);
    // GEMM3+4
    size_t lds34 = (size_t)2 * 64 * SH_STRIDE * 2;       // 133120
    fused34<<<(NOBJ + TM - 1) / TM, 512, lds34, stream>>>(xbuf, pW2a, b2a, pW2b, b2b, out_obj);
}

// Round 9
// 1031.386 us; speedup vs baseline: 2.0187x; 1.0423x over previous
//
#include <hip/hip_runtime.h>
#include <hip/hip_bf16.h>
#include <stdint.h>

typedef __bf16 bf16x8 __attribute__((ext_vector_type(8)));
typedef __bf16 bf16x4 __attribute__((ext_vector_type(4)));
typedef float  f32x4  __attribute__((ext_vector_type(4)));

#define DIN   128
#define KA    384
#define HD    512
#define NB    1152
#define DOUTD 128
#define NOBJ  50000
#define NTRI  200000
#define TM    64
#define NSCAN 98   // ceil(NOBJ/512)
#define SB_STRIDE 520

// ---------------- edges normalization (int32/int64 auto-detect, clamp) ----------------
__global__ void detect_i64(const int* __restrict__ e, int* __restrict__ flag) {
    int i = blockIdx.x * 256 + threadIdx.x;
    if (i < NTRI && e[2 * i + 1] != 0) atomicOr(flag, 1);   // odd words nonzero => int32 layout
}
__global__ void normalize_edges(const int* __restrict__ e, const int* __restrict__ flag,
                                int* __restrict__ sidx, int* __restrict__ oidx) {
    int t = blockIdx.x * 256 + threadIdx.x;
    if (t >= NTRI) return;
    bool is64 = (*flag == 0);
    int s = is64 ? e[4 * t]     : e[2 * t];
    int o = is64 ? e[4 * t + 2] : e[2 * t + 1];
    s = s < 0 ? 0 : (s >= NOBJ ? NOBJ - 1 : s);
    o = o < 0 ? 0 : (o >= NOBJ ? NOBJ - 1 : o);
    sidx[t] = s; oidx[t] = o;
}

// ---------------- weight packing: f32 row-major (K,N) -> bf16 MFMA B-fragments ----------------
// frag f = kt*(N/16) + nt ; lane l holds W[kt*32 + (l>>4)*8 + i][nt*16 + (l&15)], i=0..7
__global__ void pack_w(const float* __restrict__ W, __bf16* __restrict__ P, int K, int N) {
    int idx = blockIdx.x * 256 + threadIdx.x;
    int total = (K / 32) * (N / 16) * 64;
    if (idx >= total) return;
    int lane = idx & 63;
    int f    = idx >> 6;
    int NT   = N / 16;
    int kt = f / NT, nt = f - kt * NT;
    int krow = kt * 32 + (lane >> 4) * 8;
    int col  = nt * 16 + (lane & 15);
    __bf16 tmp[8];
#pragma unroll
    for (int i = 0; i < 8; i++) tmp[i] = (__bf16)W[(size_t)(krow + i) * N + col];
    *reinterpret_cast<bf16x8*>(P + (size_t)idx * 8) = *reinterpret_cast<const bf16x8*>(tmp);
}

// ---------------- degree counts ----------------
__global__ void count_int(const int* __restrict__ sidx, const int* __restrict__ oidx,
                          int* __restrict__ cnt) {
    int t = blockIdx.x * 256 + threadIdx.x;
    if (t >= NTRI) return;
    atomicAdd(&cnt[sidx[t]], 1);
    atomicAdd(&cnt[oidx[t]], 1);
}

// ---------------- CSR prefix scan (3 kernels) ----------------
__global__ void scanA(const int* __restrict__ cnt, int* __restrict__ sums) {
    __shared__ int sh[512];
    int idx = blockIdx.x * 512 + threadIdx.x;
    sh[threadIdx.x] = idx < NOBJ ? cnt[idx] : 0;
    __syncthreads();
    for (int s = 256; s > 0; s >>= 1) {
        if (threadIdx.x < s) sh[threadIdx.x] += sh[threadIdx.x + s];
        __syncthreads();
    }
    if (threadIdx.x == 0) sums[blockIdx.x] = sh[0];
}
__global__ void scanB(int* __restrict__ sums) {
    if (threadIdx.x == 0) {
        int run = 0;
        for (int i = 0; i < NSCAN; i++) { int v = sums[i]; sums[i] = run; run += v; }
    }
}
__global__ void scanC(const int* __restrict__ cnt, const int* __restrict__ sums,
                      int* __restrict__ offs, int* __restrict__ cursor) {
    __shared__ int sh[512];
    int idx = blockIdx.x * 512 + threadIdx.x;
    int v = idx < NOBJ ? cnt[idx] : 0;
    sh[threadIdx.x] = v;
    __syncthreads();
    for (int d = 1; d < 512; d <<= 1) {
        int t = (threadIdx.x >= d) ? sh[threadIdx.x - d] : 0;
        __syncthreads();
        sh[threadIdx.x] += t;
        __syncthreads();
    }
    if (idx < NOBJ) {
        int excl = sh[threadIdx.x] - v + sums[blockIdx.x];
        offs[idx] = excl; cursor[idx] = excl;
    }
}
__global__ void fill_refs(const int* __restrict__ sidx, const int* __restrict__ oidx,
                          int* __restrict__ cursor, int* __restrict__ refs) {
    int t = blockIdx.x * 256 + threadIdx.x;
    if (t >= NTRI) return;
    int p = atomicAdd(&cursor[sidx[t]], 1); refs[p] = 2 * t;
    int q = atomicAdd(&cursor[oidx[t]], 1); refs[q] = 2 * t + 1;
}

// ---------------- pooling: CSR gather mean -> x (bf16) ----------------
__global__ __launch_bounds__(512) void pool_mean(
    const __bf16* __restrict__ newso, const int* __restrict__ cnt,
    const int* __restrict__ offs, const int* __restrict__ refs,
    __bf16* __restrict__ xbuf)
{
    int w    = (blockIdx.x * 512 + threadIdx.x) >> 6;   // one wave per object
    int lane = threadIdx.x & 63;
    if (w >= NOBJ) return;
    int n = cnt[w], off = offs[w];
    float acc[8];
#pragma unroll
    for (int i = 0; i < 8; i++) acc[i] = 0.f;
    for (int j = 0; j < n; j++) {
        int r = refs[off + j];
        const __bf16* src = newso + (size_t)(r >> 1) * 1024 + (r & 1) * 512 + lane * 8;
        bf16x8 v = *reinterpret_cast<const bf16x8*>(src);
#pragma unroll
        for (int i = 0; i < 8; i++) acc[i] += (float)v[i];
    }
    float inv = 1.f / (n > 0 ? (float)n : 1.f);
    bf16x8 o;
#pragma unroll
    for (int i = 0; i < 8; i++) o[i] = (__bf16)(acc[i] * inv);
    *reinterpret_cast<bf16x8*>(xbuf + (size_t)w * 512 + lane * 8) = o;
}

// ---------------- fused GEMM1 + GEMM2 (1m x 8n waves, aliased LDS, B-prefetch pipeline) ----------------
__global__ __launch_bounds__(512, 4) void fused12(
    const float* __restrict__ obj, const float* __restrict__ pred,
    const int* __restrict__ sidx, const int* __restrict__ oidx,
    const __bf16* __restrict__ pW1a, const float* __restrict__ b1a,
    const __bf16* __restrict__ pW1b, const float* __restrict__ b1b,
    float* __restrict__ out_p, __bf16* __restrict__ newso)
{
    extern __shared__ char smem[];
    __bf16* sB = (__bf16*)smem;                          // 64*520*2 = 66560 B

    const int tid  = threadIdx.x;
    const int lane = tid & 63;
    const int wn   = tid >> 6;          // 0..7 : N-slice owner
    const int t0   = blockIdx.x * TM;

    const int lk    = (lane >> 4) * 8;  // K sub-offset within 32
    const int lr    = lane & 15;        // A-row / B-col / D-col
    const int rbase = (lane >> 4) * 4;  // D row base

    // ---- Phase 1: gather cur_t tile (f32 -> bf16) into LDS ----
    for (int u = tid; u < 64 * 96; u += 512) {
        int part = u & 31;
        int seg  = (u >> 5) % 3;
        int row  = u / 96;
        int t    = t0 + row;
        const float* src;
        if (seg == 0)      src = obj  + (size_t)sidx[t] * DIN;
        else if (seg == 1) src = pred + (size_t)t       * DIN;
        else               src = obj  + (size_t)oidx[t] * DIN;
        float4 v = *reinterpret_cast<const float4*>(src + part * 4);
        bf16x4 w;
        w[0] = (__bf16)v.x; w[1] = (__bf16)v.y; w[2] = (__bf16)v.z; w[3] = (__bf16)v.w;
        *reinterpret_cast<bf16x4*>(sB + row * SB_STRIDE + seg * 128 + part * 4) = w;
    }
    __syncthreads();

    // ---- GEMM1: h = relu(cur_t @ W1a + b1a); wave covers 64 rows x 64 cols ----
    {
        f32x4 acc[4][4];
#pragma unroll
        for (int mi = 0; mi < 4; mi++)
#pragma unroll
            for (int ni = 0; ni < 4; ni++) acc[mi][ni] = (f32x4){0.f, 0.f, 0.f, 0.f};

        // prefetch B for kt=0
        bf16x8 bc[4];
#pragma unroll
        for (int ni = 0; ni < 4; ni++)
            bc[ni] = *reinterpret_cast<const bf16x8*>(pW1a + (((size_t)(wn * 4 + ni)) * 64 + lane) * 8);

        for (int kt = 0; kt < KA / 32; ++kt) {
            // issue next kt's B loads first (hide L2 latency under MFMAs below)
            int ktn = (kt + 1 < KA / 32) ? kt + 1 : kt;
            bf16x8 bn[4];
#pragma unroll
            for (int ni = 0; ni < 4; ni++)
                bn[ni] = *reinterpret_cast<const bf16x8*>(pW1a + (((size_t)(ktn * 32 + wn * 4 + ni)) * 64 + lane) * 8);

            bf16x8 a[4];
#pragma unroll
            for (int mi = 0; mi < 4; mi++)
                a[mi] = *reinterpret_cast<const bf16x8*>(sB + (mi * 16 + lr) * SB_STRIDE + kt * 32 + lk);

#pragma unroll
            for (int ni = 0; ni < 4; ni++)
#pragma unroll
                for (int mi = 0; mi < 4; mi++)
                    acc[mi][ni] = __builtin_amdgcn_mfma_f32_16x16x32_bf16(a[mi], bc[ni], acc[mi][ni], 0, 0, 0);

#pragma unroll
            for (int ni = 0; ni < 4; ni++) bc[ni] = bn[ni];
        }
        __syncthreads();    // all cur_t reads complete before h overwrites the buffer

        // epilogue: bias + relu -> sB (h, bf16)
#pragma unroll
        for (int ni = 0; ni < 4; ni++) {
            int col = wn * 64 + ni * 16 + lr;
            float bv = b1a[col];
#pragma unroll
            for (int mi = 0; mi < 4; mi++)
#pragma unroll
                for (int r = 0; r < 4; r++) {
                    float v = acc[mi][ni][r] + bv;
                    v = v > 0.f ? v : 0.f;
                    sB[(mi * 16 + rbase + r) * SB_STRIDE + col] = (__bf16)v;
                }
        }
    }
    __syncthreads();

    // ---- GEMM2: new_t = relu(h @ W1b + b1b); wave covers 64 rows x 144 cols, 3 passes ----
    for (int pp = 0; pp < 3; ++pp) {
        f32x4 acc2[4][3];
#pragma unroll
        for (int mi = 0; mi < 4; mi++)
#pragma unroll
            for (int ni = 0; ni < 3; ni++) acc2[mi][ni] = (f32x4){0.f, 0.f, 0.f, 0.f};

        bf16x8 bc[3];
#pragma unroll
        for (int ni = 0; ni < 3; ni++)
            bc[ni] = *reinterpret_cast<const bf16x8*>(pW1b + (((size_t)(wn * 9 + pp * 3 + ni)) * 64 + lane) * 8);

        for (int kt = 0; kt < HD / 32; ++kt) {
            int ktn = (kt + 1 < HD / 32) ? kt + 1 : kt;
            bf16x8 bn[3];
#pragma unroll
            for (int ni = 0; ni < 3; ni++)
                bn[ni] = *reinterpret_cast<const bf16x8*>(pW1b + (((size_t)(ktn * 72 + wn * 9 + pp * 3 + ni)) * 64 + lane) * 8);

            bf16x8 a[4];
#pragma unroll
            for (int mi = 0; mi < 4; mi++)
                a[mi] = *reinterpret_cast<const bf16x8*>(sB + (mi * 16 + lr) * SB_STRIDE + kt * 32 + lk);

#pragma unroll
            for (int ni = 0; ni < 3; ni++)
#pragma unroll
                for (int mi = 0; mi < 4; mi++)
                    acc2[mi][ni] = __builtin_amdgcn_mfma_f32_16x16x32_bf16(a[mi], bc[ni], acc2[mi][ni], 0, 0, 0);

#pragma unroll
            for (int ni = 0; ni < 3; ni++) bc[ni] = bn[ni];
        }
        // epilogue: bias + relu, route (no barrier needed: only global writes)
#pragma unroll
        for (int ni = 0; ni < 3; ni++) {
            int c = wn * 144 + pp * 48 + ni * 16 + lr;
            float bv = b1b[c];
#pragma unroll
            for (int mi = 0; mi < 4; mi++)
#pragma unroll
                for (int r = 0; r < 4; r++) {
                    int row = mi * 16 + rbase + r;
                    int t   = t0 + row;
                    float v = acc2[mi][ni][r] + bv;
                    v = v > 0.f ? v : 0.f;
                    if (c < HD) {
                        newso[(size_t)t * 1024 + c] = (__bf16)v;
                    } else if (c < HD + DOUTD) {
                        out_p[(size_t)t * DOUTD + (c - HD)] = v;
                    } else {
                        newso[(size_t)t * 1024 + 512 + (c - HD - DOUTD)] = (__bf16)v;
                    }
                }
        }
    }
}

// ---------------- fused GEMM3 + GEMM4 (aliased LDS: h2 overwrites x; B-prefetch) ----------------
__global__ __launch_bounds__(512, 4) void fused34(
    const __bf16* __restrict__ xbuf,
    const __bf16* __restrict__ pW2a, const float* __restrict__ b2a,
    const __bf16* __restrict__ pW2b, const float* __restrict__ b2b,
    float* __restrict__ out_obj)
{
    extern __shared__ char smem[];
    __bf16* sX = (__bf16*)smem;                          // 64*520*2 = 66560 B (x, then h2)

    const int tid  = threadIdx.x;
    const int lane = tid & 63;
    const int wid  = tid >> 6;
    const int o0   = blockIdx.x * TM;

    // ---- Phase 1: x tile -> LDS (bf16) ----
    for (int u = tid; u < 64 * 64; u += 512) {           // 64 rows x 64 parts (8 bf16)
        int part = u & 63;
        int row  = u >> 6;
        int ob   = o0 + row;
        bf16x8 v;
        if (ob < NOBJ) v = *reinterpret_cast<const bf16x8*>(xbuf + (size_t)ob * 512 + part * 8);
        else { bf16x8 z = {}; v = z; }
        *reinterpret_cast<bf16x8*>(sX + row * SB_STRIDE + part * 8) = v;
    }
    __syncthreads();

    const int wm = wid >> 2;
    const int wn = wid & 3;
    const int lk = (lane >> 4) * 8;
    const int lr = lane & 15;
    const int rbase = (lane >> 4) * 4;

    // ---- Phase 2: h2 = relu(x @ W2a + b2a), 64x512 ----
    {
        f32x4 acc[2][8];
#pragma unroll
        for (int mi = 0; mi < 2; mi++)
#pragma unroll
            for (int ni = 0; ni < 8; ni++) acc[mi][ni] = (f32x4){0.f, 0.f, 0.f, 0.f};

        bf16x8 bc[8];
#pragma unroll
        for (int ni = 0; ni < 8; ni++)
            bc[ni] = *reinterpret_cast<const bf16x8*>(pW2a + (((size_t)(wn * 8 + ni)) * 64 + lane) * 8);

        for (int kt = 0; kt < HD / 32; ++kt) {
            int ktn = (kt + 1 < HD / 32) ? kt + 1 : kt;
            bf16x8 bn[8];
#pragma unroll
            for (int ni = 0; ni < 8; ni++)
                bn[ni] = *reinterpret_cast<const bf16x8*>(pW2a + (((size_t)(ktn * 32 + wn * 8 + ni)) * 64 + lane) * 8);

            bf16x8 a0 = *reinterpret_cast<const bf16x8*>(sX + (wm * 32 + lr) * SB_STRIDE + kt * 32 + lk);
            bf16x8 a1 = *reinterpret_cast<const bf16x8*>(sX + (wm * 32 + 16 + lr) * SB_STRIDE + kt * 32 + lk);
#pragma unroll
            for (int ni = 0; ni < 8; ni++) {
                acc[0][ni] = __builtin_amdgcn_mfma_f32_16x16x32_bf16(a0, bc[ni], acc[0][ni], 0, 0, 0);
                acc[1][ni] = __builtin_amdgcn_mfma_f32_16x16x32_bf16(a1, bc[ni], acc[1][ni], 0, 0, 0);
            }
#pragma unroll
            for (int ni = 0; ni < 8; ni++) bc[ni] = bn[ni];
        }
        __syncthreads();    // all x reads done before h2 overwrites

#pragma unroll
        for (int mi = 0; mi < 2; mi++)
#pragma unroll
            for (int ni = 0; ni < 8; ni++) {
                int col = wn * 128 + ni * 16 + lr;
                float bv = b2a[col];
#pragma unroll
                for (int r = 0; r < 4; r++) {
                    float v = acc[mi][ni][r] + bv;
                    v = v > 0.f ? v : 0.f;
                    sX[(wm * 32 + mi * 16 + rbase + r) * SB_STRIDE + col] = (__bf16)v;
                }
            }
    }
    __syncthreads();

    // ---- Phase 3: new_obj = relu(h2 @ W2b + b2b), 64x128 ----
    {
        f32x4 acc[2][2];
#pragma unroll
        for (int mi = 0; mi < 2; mi++)
#pragma unroll
            for (int ni = 0; ni < 2; ni++) acc[mi][ni] = (f32x4){0.f, 0.f, 0.f, 0.f};

        for (int kt = 0; kt < HD / 32; ++kt) {
            bf16x8 a0 = *reinterpret_cast<const bf16x8*>(sX + (wm * 32 + lr) * SB_STRIDE + kt * 32 + lk);
            bf16x8 a1 = *reinterpret_cast<const bf16x8*>(sX + (wm * 32 + 16 + lr) * SB_STRIDE + kt * 32 + lk);
#pragma unroll
            for (int ni = 0; ni < 2; ni++) {
                int f = kt * 8 + wn * 2 + ni;
                bf16x8 b = *reinterpret_cast<const bf16x8*>(pW2b + ((size_t)f * 64 + lane) * 8);
                acc[0][ni] = __builtin_amdgcn_mfma_f32_16x16x32_bf16(a0, b, acc[0][ni], 0, 0, 0);
                acc[1][ni] = __builtin_amdgcn_mfma_f32_16x16x32_bf16(a1, b, acc[1][ni], 0, 0, 0);
            }
        }
#pragma unroll
        for (int mi = 0; mi < 2; mi++)
#pragma unroll
            for (int ni = 0; ni < 2; ni++) {
                int col = wn * 32 + ni * 16 + lr;
                float bv = b2b[col];
#pragma unroll
                for (int r = 0; r < 4; r++) {
                    int row = wm * 32 + mi * 16 + rbase + r;
                    int ob  = o0 + row;
                    if (ob < NOBJ) {
                        float v = acc[mi][ni][r] + bv;
                        v = v > 0.f ? v : 0.f;
                        out_obj[(size_t)ob * DOUTD + col] = v;
                    }
                }
            }
    }
}

// ---------------- launch ----------------
extern "C" void kernel_launch(void* const* d_in, const int* in_sizes, int n_in,
                              void* d_out, int out_size, void* d_ws, size_t ws_size,
                              hipStream_t stream)
{
    const float* obj   = (const float*)d_in[0];
    const float* pred  = (const float*)d_in[1];
    const int*   edges = (const int*)d_in[2];
    const float* W1a = (const float*)d_in[3];
    const float* b1a = (const float*)d_in[4];
    const float* W1b = (const float*)d_in[5];
    const float* b1b = (const float*)d_in[6];
    const float* W2a = (const float*)d_in[7];
    const float* b2a = (const float*)d_in[8];
    const float* W2b = (const float*)d_in[9];
    const float* b2b = (const float*)d_in[10];

    float* out_obj = (float*)d_out;
    float* out_p   = (float*)d_out + (size_t)NOBJ * DOUTD;

    // ws layout (bytes) — proven to fit (fast path engaged since R7):
    char* ws = (char*)d_ws;
    int*    sidx   = (int*)ws;
    int*    oidx   = sidx + NTRI;
    int*    flag   = (int*)(ws + 1800000);
    __bf16* pW1a   = (__bf16*)(ws + 1800064);
    __bf16* pW1b   = pW1a + 196608;
    __bf16* pW2a   = pW1b + 589824;
    __bf16* pW2b   = pW2a + 262144;
    int*    cnt    = (int*)(ws + 4028416);
    int*    offs   = (int*)(ws + 4228416);
    int*    cursor = (int*)(ws + 4428416);
    int*    sums   = (int*)(ws + 4628416);
    int*    refs   = (int*)(ws + 4628928);
    __bf16* xbuf   = (__bf16*)(ws + 6228928);
    __bf16* newso  = (__bf16*)(ws + 57428928);

    hipMemsetAsync(flag, 0, 4, stream);
    detect_i64<<<(NTRI + 255) / 256, 256, 0, stream>>>(edges, flag);
    normalize_edges<<<(NTRI + 255) / 256, 256, 0, stream>>>(edges, flag, sidx, oidx);

    pack_w<<<(24576 + 255) / 256, 256, 0, stream>>>(W1a, pW1a, 384, 512);
    pack_w<<<(73728 + 255) / 256, 256, 0, stream>>>(W1b, pW1b, 512, 1152);
    pack_w<<<(32768 + 255) / 256, 256, 0, stream>>>(W2a, pW2a, 512, 512);
    pack_w<<<(8192  + 255) / 256, 256, 0, stream>>>(W2b, pW2b, 512, 128);

    // CSR build
    hipMemsetAsync(cnt, 0, 200000, stream);
    count_int<<<(NTRI + 255) / 256, 256, 0, stream>>>(sidx, oidx, cnt);
    scanA<<<NSCAN, 512, 0, stream>>>(cnt, sums);
    scanB<<<1, 64, 0, stream>>>(sums);
    scanC<<<NSCAN, 512, 0, stream>>>(cnt, sums, offs, cursor);
    fill_refs<<<(NTRI + 255) / 256, 256, 0, stream>>>(sidx, oidx, cursor, refs);

    // GEMM1+2 (fused, streaming writes)
    size_t lds12 = (size_t)64 * SB_STRIDE * 2;           // 66560 -> 2 blocks/CU
    fused12<<<NTRI / TM, 512, lds12, stream>>>(obj, pred, sidx, oidx,
                                               pW1a, b1a, pW1b, b1b,
                                               out_p, newso);
    // segment mean
    pool_mean<<<(NOBJ * 64 + 511) / 512, 512, 0, stream>>>(newso, cnt, offs, refs, xbuf);
    // GEMM3+4
    size_t lds34 = (size_t)64 * SB_STRIDE * 2;           // 66560 -> 2 blocks/CU
    fused34<<<(NOBJ + TM - 1) / TM, 512, lds34, stream>>>(xbuf, pW2a, b2a, pW2b, b2b, out_obj);
}